// Round 1
// baseline (3888.609 us; speedup 1.0000x reference)
//
#include <hip/hip_runtime.h>

#define NN 100000
#define NE 1600000
#define ETOT (NE + NN)
#define NEG 0.2f

// ordered-uint encoding so atomicMax(uint) == float max
__device__ __forceinline__ unsigned fenc(float f) {
    unsigned b = __float_as_uint(f);
    return (b & 0x80000000u) ? ~b : (b | 0x80000000u);
}
__device__ __forceinline__ float fdec(unsigned k) {
    return (k & 0x80000000u) ? __uint_as_float(k & 0x7FFFFFFFu) : __uint_as_float(~k);
}

// ---------------- Layer 1: per-node h1, a_s, a_d + init accumulators ----------------
__global__ __launch_bounds__(256) void k1_node(
    const float* __restrict__ x, const float* __restrict__ W1,
    const float* __restrict__ atts, const float* __restrict__ attd,
    float* __restrict__ h1, float* __restrict__ as1, float* __restrict__ ad1,
    unsigned* __restrict__ m1, float* __restrict__ den1, float* __restrict__ out1)
{
    __shared__ float sW[256], sAs[64], sAd[64];
    int t = threadIdx.x;
    sW[t] = W1[t];
    if (t < 64) { sAs[t] = atts[t]; sAd[t] = attd[t]; }
    __syncthreads();
    int n = blockIdx.x * 256 + t;
    if (n >= NN) return;
    float4 xv = *reinterpret_cast<const float4*>(&x[(size_t)n * 4]);
    float as[8], ad[8], hrow[64];
    #pragma unroll
    for (int h = 0; h < 8; h++) { as[h] = 0.f; ad[h] = 0.f; }
    #pragma unroll
    for (int j = 0; j < 64; j++) {
        float hv = xv.x * sW[j] + xv.y * sW[64 + j] + xv.z * sW[128 + j] + xv.w * sW[192 + j];
        hrow[j] = hv;
        int h = j >> 3;
        as[h] += hv * sAs[j];
        ad[h] += hv * sAd[j];
    }
    #pragma unroll
    for (int j = 0; j < 64; j += 4) {
        *reinterpret_cast<float4*>(&h1[(size_t)n * 64 + j]) =
            make_float4(hrow[j], hrow[j + 1], hrow[j + 2], hrow[j + 3]);
        *reinterpret_cast<float4*>(&out1[(size_t)n * 64 + j]) = make_float4(0.f, 0.f, 0.f, 0.f);
    }
    #pragma unroll
    for (int h = 0; h < 8; h++) {
        as1[n * 8 + h] = as[h];
        ad1[n * 8 + h] = ad[h];
        m1[n * 8 + h] = 0u;       // fenc(-inf) lower bound
        den1[n * 8 + h] = 0.f;
    }
}

// ---------------- Layer 1: edge max ----------------
__global__ __launch_bounds__(256) void k2_edge_max(
    const int* __restrict__ ei, const float* __restrict__ as1,
    const float* __restrict__ ad1, unsigned* __restrict__ m1)
{
    int e = blockIdx.x * 256 + threadIdx.x;
    if (e >= ETOT) return;
    int s, d;
    if (e < NE) { s = ei[e]; d = ei[NE + e]; } else { s = d = e - NE; }
    float4 a0 = *reinterpret_cast<const float4*>(&as1[s * 8]);
    float4 a1 = *reinterpret_cast<const float4*>(&as1[s * 8 + 4]);
    float4 b0 = *reinterpret_cast<const float4*>(&ad1[d * 8]);
    float4 b1 = *reinterpret_cast<const float4*>(&ad1[d * 8 + 4]);
    float v[8] = {a0.x + b0.x, a0.y + b0.y, a0.z + b0.z, a0.w + b0.w,
                  a1.x + b1.x, a1.y + b1.y, a1.z + b1.z, a1.w + b1.w};
    #pragma unroll
    for (int h = 0; h < 8; h++) {
        float vv = v[h] > 0.f ? v[h] : NEG * v[h];
        atomicMax(&m1[d * 8 + h], fenc(vv));
    }
}

// ---------------- Layer 1: edge exp + unnormalized aggregate ----------------
__global__ __launch_bounds__(256) void k3_edge_agg(
    const int* __restrict__ ei, const float* __restrict__ as1,
    const float* __restrict__ ad1, const unsigned* __restrict__ m1,
    const float* __restrict__ h1, float* __restrict__ den1, float* __restrict__ out1)
{
    long long idx = (long long)blockIdx.x * 256 + threadIdx.x;
    if (idx >= (long long)ETOT * 8) return;
    int e = (int)(idx >> 3);
    int h = (int)(idx & 7);
    int s, d;
    if (e < NE) { s = ei[e]; d = ei[NE + e]; } else { s = d = e - NE; }
    float v = as1[s * 8 + h] + ad1[d * 8 + h];
    v = v > 0.f ? v : NEG * v;
    float m = fdec(m1[d * 8 + h]);
    float p = __expf(v - m);
    atomicAdd(&den1[d * 8 + h], p);
    float4 h0 = *reinterpret_cast<const float4*>(&h1[(size_t)s * 64 + h * 8]);
    float4 h1v = *reinterpret_cast<const float4*>(&h1[(size_t)s * 64 + h * 8 + 4]);
    float* op = &out1[(size_t)d * 64 + h * 8];
    atomicAdd(op + 0, p * h0.x);
    atomicAdd(op + 1, p * h0.y);
    atomicAdd(op + 2, p * h0.z);
    atomicAdd(op + 3, p * h0.w);
    atomicAdd(op + 4, p * h1v.x);
    atomicAdd(op + 5, p * h1v.y);
    atomicAdd(op + 6, p * h1v.z);
    atomicAdd(op + 7, p * h1v.w);
}

// ---------------- Layer 2: per-node normalize + ELU + dot(W2) ----------------
__global__ __launch_bounds__(256) void k4_node2(
    const float* __restrict__ out1, const float* __restrict__ den1,
    const float* __restrict__ b1, const float* __restrict__ W2,
    float* __restrict__ h2, unsigned* __restrict__ m2,
    float* __restrict__ den2, float* __restrict__ num2)
{
    __shared__ float sW2[64], sB1[64];
    int t = threadIdx.x;
    if (t < 64) { sW2[t] = W2[t]; sB1[t] = b1[t]; }
    __syncthreads();
    int n = blockIdx.x * 256 + t;
    if (n >= NN) return;
    float acc = 0.f;
    #pragma unroll
    for (int h = 0; h < 8; h++) {
        float dinv = 1.f / (den1[n * 8 + h] + 1e-16f);
        #pragma unroll
        for (int c = 0; c < 8; c++) {
            int j = h * 8 + c;
            float v = out1[(size_t)n * 64 + j] * dinv + sB1[j];
            v = v > 0.f ? v : (__expf(v) - 1.f);   // ELU
            acc += v * sW2[j];
        }
    }
    h2[n] = acc;
    m2[n] = 0u;
    den2[n] = 0.f;
    num2[n] = 0.f;
}

// ---------------- Layer 2: edge max ----------------
__global__ __launch_bounds__(256) void k5_edge2_max(
    const int* __restrict__ ei, const float* __restrict__ h2,
    const float* __restrict__ as2, const float* __restrict__ ad2,
    unsigned* __restrict__ m2)
{
    int e = blockIdx.x * 256 + threadIdx.x;
    if (e >= ETOT) return;
    int s, d;
    if (e < NE) { s = ei[e]; d = ei[NE + e]; } else { s = d = e - NE; }
    float v = h2[s] * as2[0] + h2[d] * ad2[0];
    v = v > 0.f ? v : NEG * v;
    atomicMax(&m2[d], fenc(v));
}

// ---------------- Layer 2: edge aggregate ----------------
__global__ __launch_bounds__(256) void k6_edge2_agg(
    const int* __restrict__ ei, const float* __restrict__ h2,
    const float* __restrict__ as2, const float* __restrict__ ad2,
    const unsigned* __restrict__ m2, float* __restrict__ den2, float* __restrict__ num2)
{
    int e = blockIdx.x * 256 + threadIdx.x;
    if (e >= ETOT) return;
    int s, d;
    if (e < NE) { s = ei[e]; d = ei[NE + e]; } else { s = d = e - NE; }
    float hs = h2[s];
    float v = hs * as2[0] + h2[d] * ad2[0];
    v = v > 0.f ? v : NEG * v;
    float p = __expf(v - fdec(m2[d]));
    atomicAdd(&den2[d], p);
    atomicAdd(&num2[d], p * hs);
}

// ---------------- Final: sigmoid ----------------
__global__ __launch_bounds__(256) void k7_final(
    const float* __restrict__ num2, const float* __restrict__ den2,
    const float* __restrict__ b2, float* __restrict__ out)
{
    int n = blockIdx.x * 256 + threadIdx.x;
    if (n >= NN) return;
    float v = num2[n] / (den2[n] + 1e-16f) + b2[0];
    out[n] = 1.f / (1.f + __expf(-v));
}

extern "C" void kernel_launch(void* const* d_in, const int* in_sizes, int n_in,
                              void* d_out, int out_size, void* d_ws, size_t ws_size,
                              hipStream_t stream) {
    const float* x     = (const float*)d_in[0];
    const int*   ei    = (const int*)d_in[1];
    const float* W1    = (const float*)d_in[2];
    const float* atts1 = (const float*)d_in[3];
    const float* attd1 = (const float*)d_in[4];
    const float* b1    = (const float*)d_in[5];
    const float* W2    = (const float*)d_in[6];
    const float* atts2 = (const float*)d_in[7];
    const float* attd2 = (const float*)d_in[8];
    const float* b2    = (const float*)d_in[9];
    float* out = (float*)d_out;

    float* w = (float*)d_ws;
    float*    h1   = w;                         // 64N
    float*    as1  = w + (size_t)64 * NN;       // 8N
    float*    ad1  = w + (size_t)72 * NN;       // 8N
    unsigned* m1   = (unsigned*)(w + (size_t)80 * NN);  // 8N
    float*    den1 = w + (size_t)88 * NN;       // 8N
    float*    out1 = w + (size_t)96 * NN;       // 64N
    float*    h2   = w + (size_t)160 * NN;      // N
    unsigned* m2   = (unsigned*)(w + (size_t)161 * NN); // N
    float*    den2 = w + (size_t)162 * NN;      // N
    float*    num2 = w + (size_t)163 * NN;      // N

    dim3 blk(256);
    dim3 gN((NN + 255) / 256);
    dim3 gE((ETOT + 255) / 256);
    dim3 gE8(((size_t)ETOT * 8 + 255) / 256);

    hipLaunchKernelGGL(k1_node, gN, blk, 0, stream, x, W1, atts1, attd1,
                       h1, as1, ad1, m1, den1, out1);
    hipLaunchKernelGGL(k2_edge_max, gE, blk, 0, stream, ei, as1, ad1, m1);
    hipLaunchKernelGGL(k3_edge_agg, gE8, blk, 0, stream, ei, as1, ad1, m1, h1, den1, out1);
    hipLaunchKernelGGL(k4_node2, gN, blk, 0, stream, out1, den1, b1, W2, h2, m2, den2, num2);
    hipLaunchKernelGGL(k5_edge2_max, gE, blk, 0, stream, ei, h2, atts2, attd2, m2);
    hipLaunchKernelGGL(k6_edge2_agg, gE, blk, 0, stream, ei, h2, atts2, attd2, m2, den2, num2);
    hipLaunchKernelGGL(k7_final, gN, blk, 0, stream, num2, den2, b2, out);
}

// Round 2
// 446.353 us; speedup vs baseline: 8.7120x; 8.7120x over previous
//
#include <hip/hip_runtime.h>

#define NN 100000
#define NE 1600000
#define ETOT (NE + NN)
#define NB1 ((NN + 255) / 256)   // 391 scan blocks
#define NEG 0.2f

// ---------------- kA: per-node h1, a_s, a_d; zero hist ----------------
__global__ __launch_bounds__(256) void kA_node(
    const float* __restrict__ x, const float* __restrict__ W1,
    const float* __restrict__ atts, const float* __restrict__ attd,
    float* __restrict__ h1, float* __restrict__ as1, float* __restrict__ ad1,
    int* __restrict__ cnt)
{
    __shared__ float sW[256], sAs[64], sAd[64];
    int t = threadIdx.x;
    sW[t] = W1[t];
    if (t < 64) { sAs[t] = atts[t]; sAd[t] = attd[t]; }
    __syncthreads();
    int n = blockIdx.x * 256 + t;
    if (n >= NN) return;
    cnt[n] = 0;
    float4 xv = *reinterpret_cast<const float4*>(&x[(size_t)n * 4]);
    float as[8], ad[8];
    #pragma unroll
    for (int h = 0; h < 8; h++) { as[h] = 0.f; ad[h] = 0.f; }
    #pragma unroll
    for (int j = 0; j < 64; j += 4) {
        float4 hv;
        float* hp = (float*)&hv;
        #pragma unroll
        for (int c = 0; c < 4; c++) {
            int jj = j + c;
            float v = xv.x * sW[jj] + xv.y * sW[64 + jj] + xv.z * sW[128 + jj] + xv.w * sW[192 + jj];
            hp[c] = v;
            int h = jj >> 3;
            as[h] += v * sAs[jj];
            ad[h] += v * sAd[jj];
        }
        *reinterpret_cast<float4*>(&h1[(size_t)n * 64 + j]) = hv;
    }
    #pragma unroll
    for (int h = 0; h < 8; h++) {
        as1[n * 8 + h] = as[h];
        ad1[n * 8 + h] = ad[h];
    }
}

// ---------------- kB: histogram of destinations ----------------
__global__ __launch_bounds__(256) void kB_hist(
    const int* __restrict__ ei, int* __restrict__ cnt)
{
    int e = blockIdx.x * 256 + threadIdx.x;
    if (e >= ETOT) return;
    int d = (e < NE) ? ei[NE + e] : (e - NE);
    atomicAdd(&cnt[d], 1);
}

// ---------------- kC1: per-block inclusive scan ----------------
__global__ __launch_bounds__(256) void kC1_scan(
    const int* __restrict__ cnt, int* __restrict__ row, int* __restrict__ bsum)
{
    __shared__ int s[256];
    int t = threadIdx.x, i = blockIdx.x * 256 + t;
    int v = (i < NN) ? cnt[i] : 0;
    s[t] = v;
    __syncthreads();
    #pragma unroll
    for (int o = 1; o < 256; o <<= 1) {
        int u = (t >= o) ? s[t - o] : 0;
        __syncthreads();
        s[t] += u;
        __syncthreads();
    }
    if (i < NN) row[i] = s[t] - v;          // exclusive within block
    if (t == 255) bsum[blockIdx.x] = s[255];
}

// ---------------- kC2: scan of block sums (single block) ----------------
__global__ __launch_bounds__(512) void kC2_scan(int* __restrict__ bsum)
{
    __shared__ int s[512];
    int t = threadIdx.x;
    int v = (t < NB1) ? bsum[t] : 0;
    s[t] = v;
    __syncthreads();
    #pragma unroll
    for (int o = 1; o < 512; o <<= 1) {
        int u = (t >= o) ? s[t - o] : 0;
        __syncthreads();
        s[t] += u;
        __syncthreads();
    }
    if (t < NB1) bsum[t] = s[t] - v;        // exclusive
}

// ---------------- kC3: add block offsets; init cursor ----------------
__global__ __launch_bounds__(256) void kC3_fix(
    int* __restrict__ row, const int* __restrict__ bsum, int* __restrict__ cursor)
{
    int i = blockIdx.x * 256 + threadIdx.x;
    if (i >= NN) return;
    int r = row[i] + bsum[i >> 8];
    row[i] = r;
    cursor[i] = r;
    if (i == 0) row[NN] = ETOT;
}

// ---------------- kD: scatter edge sources into CSR ----------------
__global__ __launch_bounds__(256) void kD_scatter(
    const int* __restrict__ ei, int* __restrict__ cursor, int* __restrict__ esrc)
{
    int e = blockIdx.x * 256 + threadIdx.x;
    if (e >= ETOT) return;
    int s, d;
    if (e < NE) { s = ei[e]; d = ei[NE + e]; } else { s = d = e - NE; }
    int pos = atomicAdd(&cursor[d], 1);
    esrc[pos] = s;
}

// ---------------- kE: layer-1 aggregate + normalize + ELU + W2 dot (wave/dst) ----------------
__global__ __launch_bounds__(256) void kE_l1agg(
    const int* __restrict__ row, const int* __restrict__ esrc,
    const float* __restrict__ as1, const float* __restrict__ ad1,
    const float* __restrict__ h1, const float* __restrict__ b1,
    const float* __restrict__ W2, float* __restrict__ h2)
{
    int wave = blockIdx.x * 4 + (threadIdx.x >> 6);
    int lane = threadIdx.x & 63;
    if (wave >= NN) return;
    int dst = wave;
    int start = row[dst], end = row[dst + 1];

    // pass 1: per-head max of as1[src]; lane = (slot t = lane>>3, head h = lane&7)
    int h = lane & 7;
    float vm = -3.0e38f;
    for (int i = start + (lane >> 3); i < end; i += 8)
        vm = fmaxf(vm, as1[esrc[i] * 8 + h]);
    vm = fmaxf(vm, __shfl_xor(vm, 8));
    vm = fmaxf(vm, __shfl_xor(vm, 16));
    vm = fmaxf(vm, __shfl_xor(vm, 32));
    float adv = ad1[dst * 8 + h];
    float mh = vm + adv;
    mh = mh > 0.f ? mh : NEG * mh;          // leaky is monotone: max logit

    // redistribute to channel layout: lane j (channel) needs head j>>3
    int myh = lane >> 3;
    float m   = __shfl(mh, myh);
    float adj = __shfl(adv, myh);

    // pass 2: channel-parallel accumulate (lane = channel)
    float acc = 0.f, den = 0.f;
    for (int i = start; i < end; ++i) {
        int s = esrc[i];
        float asv = as1[s * 8 + myh];
        float v = asv + adj;
        v = v > 0.f ? v : NEG * v;
        float p = __expf(v - m);
        den += p;
        acc += p * h1[(size_t)s * 64 + lane];
    }

    // fused: normalize + b1 + ELU + W2 dot, wave-reduce
    float v = acc / (den + 1e-16f) + b1[lane];
    v = v > 0.f ? v : (__expf(v) - 1.f);
    float w = v * W2[lane];
    #pragma unroll
    for (int o = 32; o; o >>= 1) w += __shfl_xor(w, o);
    if (lane == 0) h2[dst] = w;
}

// ---------------- kF: layer-2 aggregate + sigmoid (wave/dst) ----------------
__global__ __launch_bounds__(256) void kF_l2agg(
    const int* __restrict__ row, const int* __restrict__ esrc,
    const float* __restrict__ h2, const float* __restrict__ as2,
    const float* __restrict__ ad2, const float* __restrict__ b2,
    float* __restrict__ out)
{
    int wave = blockIdx.x * 4 + (threadIdx.x >> 6);
    int lane = threadIdx.x & 63;
    if (wave >= NN) return;
    int dst = wave;
    int start = row[dst], end = row[dst + 1];
    float a_s = as2[0], a_d = ad2[0];
    float hd = h2[dst] * a_d;

    // pass 1: max logit (lanes parallel over edges)
    float vm = -3.0e38f;
    for (int i = start + lane; i < end; i += 64) {
        float v = h2[esrc[i]] * a_s + hd;
        v = v > 0.f ? v : NEG * v;
        vm = fmaxf(vm, v);
    }
    #pragma unroll
    for (int o = 32; o; o >>= 1) vm = fmaxf(vm, __shfl_xor(vm, o));

    // pass 2: exp-sum
    float den = 0.f, num = 0.f;
    for (int i = start + lane; i < end; i += 64) {
        float hs = h2[esrc[i]];
        float v = hs * a_s + hd;
        v = v > 0.f ? v : NEG * v;
        float p = __expf(v - vm);
        den += p;
        num += p * hs;
    }
    #pragma unroll
    for (int o = 32; o; o >>= 1) {
        den += __shfl_xor(den, o);
        num += __shfl_xor(num, o);
    }
    if (lane == 0) {
        float v = num / (den + 1e-16f) + b2[0];
        out[dst] = 1.f / (1.f + __expf(-v));
    }
}

extern "C" void kernel_launch(void* const* d_in, const int* in_sizes, int n_in,
                              void* d_out, int out_size, void* d_ws, size_t ws_size,
                              hipStream_t stream) {
    const float* x     = (const float*)d_in[0];
    const int*   ei    = (const int*)d_in[1];
    const float* W1    = (const float*)d_in[2];
    const float* atts1 = (const float*)d_in[3];
    const float* attd1 = (const float*)d_in[4];
    const float* b1    = (const float*)d_in[5];
    const float* W2    = (const float*)d_in[6];
    const float* atts2 = (const float*)d_in[7];
    const float* attd2 = (const float*)d_in[8];
    const float* b2    = (const float*)d_in[9];
    float* out = (float*)d_out;

    float* w = (float*)d_ws;
    float* h1     = w;                                  // 64N
    float* as1    = w + (size_t)64 * NN;                // 8N
    float* ad1    = w + (size_t)72 * NN;                // 8N
    float* h2     = w + (size_t)80 * NN;                // N
    int*   cnt    = (int*)(w + (size_t)81 * NN);        // N
    int*   row    = (int*)(w + (size_t)82 * NN);        // N+1
    int*   cursor = (int*)(w + (size_t)84 * NN);        // N
    int*   bsum   = (int*)(w + (size_t)85 * NN);        // NB1
    int*   esrc   = (int*)(w + (size_t)86 * NN);        // ETOT

    dim3 blk(256);
    dim3 gN((NN + 255) / 256);
    dim3 gE((ETOT + 255) / 256);
    dim3 gW((NN + 3) / 4);   // wave per node, 4 waves/block

    hipLaunchKernelGGL(kA_node, gN, blk, 0, stream, x, W1, atts1, attd1, h1, as1, ad1, cnt);
    hipLaunchKernelGGL(kB_hist, gE, blk, 0, stream, ei, cnt);
    hipLaunchKernelGGL(kC1_scan, dim3(NB1), blk, 0, stream, cnt, row, bsum);
    hipLaunchKernelGGL(kC2_scan, dim3(1), dim3(512), 0, stream, bsum);
    hipLaunchKernelGGL(kC3_fix, gN, blk, 0, stream, row, bsum, cursor);
    hipLaunchKernelGGL(kD_scatter, gE, blk, 0, stream, ei, cursor, esrc);
    hipLaunchKernelGGL(kE_l1agg, gW, blk, 0, stream, row, esrc, as1, ad1, h1, b1, W2, h2);
    hipLaunchKernelGGL(kF_l2agg, gW, blk, 0, stream, row, esrc, h2, atts2, attd2, b2, out);
}

// Round 3
// 329.389 us; speedup vs baseline: 11.8055x; 1.3551x over previous
//
#include <hip/hip_runtime.h>

#define NN 100000
#define NE 1600000
#define ETOT (NE + NN)
#define NB1 ((NN + 255) / 256)   // 391 scan blocks
#define NEG 0.2f

// ---------------- kU: precompute u_s[8][4], u_d[8][4] (W1 · att vectors) ----------------
__global__ void kU_prep(
    const float* __restrict__ W1, const float* __restrict__ atts,
    const float* __restrict__ attd, float* __restrict__ us, float* __restrict__ ud)
{
    int t = threadIdx.x;           // 64 threads
    if (t >= 64) return;
    int half = t >> 5;             // 0: us, 1: ud
    int i = t & 31;
    int h = i >> 2, k = i & 3;
    const float* att = half ? attd : atts;
    float acc = 0.f;
    #pragma unroll
    for (int j = 0; j < 8; j++)
        acc += W1[k * 64 + h * 8 + j] * att[h * 8 + j];
    (half ? ud : us)[h * 4 + k] = acc;
}

// ---------------- kB: histogram of destinations ----------------
__global__ __launch_bounds__(256) void kB_hist(
    const int* __restrict__ ei, int* __restrict__ cnt)
{
    int e = blockIdx.x * 256 + threadIdx.x;
    if (e >= ETOT) return;
    int d = (e < NE) ? ei[NE + e] : (e - NE);
    atomicAdd(&cnt[d], 1);
}

// ---------------- kC1: per-block inclusive scan ----------------
__global__ __launch_bounds__(256) void kC1_scan(
    const int* __restrict__ cnt, int* __restrict__ row, int* __restrict__ bsum)
{
    __shared__ int s[256];
    int t = threadIdx.x, i = blockIdx.x * 256 + t;
    int v = (i < NN) ? cnt[i] : 0;
    s[t] = v;
    __syncthreads();
    #pragma unroll
    for (int o = 1; o < 256; o <<= 1) {
        int u = (t >= o) ? s[t - o] : 0;
        __syncthreads();
        s[t] += u;
        __syncthreads();
    }
    if (i < NN) row[i] = s[t] - v;          // exclusive within block
    if (t == 255) bsum[blockIdx.x] = s[255];
}

// ---------------- kC2: scan of block sums (single block) ----------------
__global__ __launch_bounds__(512) void kC2_scan(int* __restrict__ bsum)
{
    __shared__ int s[512];
    int t = threadIdx.x;
    int v = (t < NB1) ? bsum[t] : 0;
    s[t] = v;
    __syncthreads();
    #pragma unroll
    for (int o = 1; o < 512; o <<= 1) {
        int u = (t >= o) ? s[t - o] : 0;
        __syncthreads();
        s[t] += u;
        __syncthreads();
    }
    if (t < NB1) bsum[t] = s[t] - v;        // exclusive
}

// ---------------- kC3: add block offsets; init cursor ----------------
__global__ __launch_bounds__(256) void kC3_fix(
    int* __restrict__ row, const int* __restrict__ bsum, int* __restrict__ cursor)
{
    int i = blockIdx.x * 256 + threadIdx.x;
    if (i >= NN) return;
    int r = row[i] + bsum[i >> 8];
    row[i] = r;
    cursor[i] = r;
    if (i == 0) row[NN] = ETOT;
}

// ---------------- kD: scatter edge sources into CSR ----------------
__global__ __launch_bounds__(256) void kD_scatter(
    const int* __restrict__ ei, int* __restrict__ cursor, int* __restrict__ esrc)
{
    int e = blockIdx.x * 256 + threadIdx.x;
    if (e >= ETOT) return;
    int s, d;
    if (e < NE) { s = ei[e]; d = ei[NE + e]; } else { s = d = e - NE; }
    int pos = atomicAdd(&cursor[d], 1);
    esrc[pos] = s;
}

// ---------------- kE: layer-1 full (recompute-from-x) + ELU + W2 dot (wave/dst) ----------------
__global__ __launch_bounds__(256) void kE_l1agg(
    const int* __restrict__ row, const int* __restrict__ esrc,
    const float* __restrict__ x, const float* __restrict__ us,
    const float* __restrict__ ud, const float* __restrict__ W1,
    const float* __restrict__ b1, const float* __restrict__ W2,
    float* __restrict__ h2)
{
    int wave = blockIdx.x * 4 + (threadIdx.x >> 6);
    int lane = threadIdx.x & 63;
    if (wave >= NN) return;
    int dst = wave;
    int start = row[dst], end = row[dst + 1];
    int myh = lane >> 3;

    // per-lane constants: W1 column (4), u_s for my head (4)
    float w0 = W1[lane], w1 = W1[64 + lane], w2 = W1[128 + lane], w3 = W1[192 + lane];
    float4 u  = *reinterpret_cast<const float4*>(&us[myh * 4]);
    float4 vd = *reinterpret_cast<const float4*>(&ud[myh * 4]);
    float4 xd = *reinterpret_cast<const float4*>(&x[(size_t)dst * 4]);
    float adj = xd.x * vd.x + xd.y * vd.y + xd.z * vd.z + xd.w * vd.w;

    float acc = 0.f, den = 0.f;
    #pragma unroll 4
    for (int i = start; i < end; ++i) {
        int s = esrc[i];
        float4 xs = *reinterpret_cast<const float4*>(&x[(size_t)s * 4]);
        float asv = xs.x * u.x + xs.y * u.y + xs.z * u.z + xs.w * u.w;
        float v = asv + adj;
        v = v > 0.f ? v : NEG * v;            // leaky_relu
        float p = __expf(v);                  // softmax is shift-invariant; logits bounded
        den += p;
        float hc = xs.x * w0 + xs.y * w1 + xs.z * w2 + xs.w * w3;
        acc += p * hc;
    }

    // normalize + b1 + ELU + W2 dot, wave-reduce
    float v = acc / (den + 1e-16f) + b1[lane];
    v = v > 0.f ? v : (__expf(v) - 1.f);
    float w = v * W2[lane];
    #pragma unroll
    for (int o = 32; o; o >>= 1) w += __shfl_xor(w, o);
    if (lane == 0) h2[dst] = w;
}

// ---------------- kF: layer-2 aggregate + sigmoid (wave/dst, single pass) ----------------
__global__ __launch_bounds__(256) void kF_l2agg(
    const int* __restrict__ row, const int* __restrict__ esrc,
    const float* __restrict__ h2, const float* __restrict__ as2,
    const float* __restrict__ ad2, const float* __restrict__ b2,
    float* __restrict__ out)
{
    int wave = blockIdx.x * 4 + (threadIdx.x >> 6);
    int lane = threadIdx.x & 63;
    if (wave >= NN) return;
    int dst = wave;
    int start = row[dst], end = row[dst + 1];
    float a_s = as2[0], a_d = ad2[0];
    float hd = h2[dst] * a_d;

    float den = 0.f, num = 0.f;
    for (int i = start + lane; i < end; i += 64) {
        float hs = h2[esrc[i]];
        float v = hs * a_s + hd;
        v = v > 0.f ? v : NEG * v;
        float p = __expf(v);
        den += p;
        num += p * hs;
    }
    #pragma unroll
    for (int o = 32; o; o >>= 1) {
        den += __shfl_xor(den, o);
        num += __shfl_xor(num, o);
    }
    if (lane == 0) {
        float v = num / (den + 1e-16f) + b2[0];
        out[dst] = 1.f / (1.f + __expf(-v));
    }
}

extern "C" void kernel_launch(void* const* d_in, const int* in_sizes, int n_in,
                              void* d_out, int out_size, void* d_ws, size_t ws_size,
                              hipStream_t stream) {
    const float* x     = (const float*)d_in[0];
    const int*   ei    = (const int*)d_in[1];
    const float* W1    = (const float*)d_in[2];
    const float* atts1 = (const float*)d_in[3];
    const float* attd1 = (const float*)d_in[4];
    const float* b1    = (const float*)d_in[5];
    const float* W2    = (const float*)d_in[6];
    const float* atts2 = (const float*)d_in[7];
    const float* attd2 = (const float*)d_in[8];
    const float* b2    = (const float*)d_in[9];
    float* out = (float*)d_out;

    float* w = (float*)d_ws;
    float* us     = w;                                  // 32
    float* ud     = w + 32;                             // 32
    float* h2     = w + 64;                             // N
    int*   cnt    = (int*)(w + 64 + (size_t)NN);        // N
    int*   row    = (int*)(w + 64 + (size_t)2 * NN);    // N+1
    int*   cursor = (int*)(w + 64 + (size_t)3 * NN + 64); // N
    int*   bsum   = (int*)(w + 64 + (size_t)4 * NN + 64); // NB1
    int*   esrc   = (int*)(w + 64 + (size_t)5 * NN + 64); // ETOT

    dim3 blk(256);
    dim3 gN((NN + 255) / 256);
    dim3 gE((ETOT + 255) / 256);
    dim3 gW((NN + 3) / 4);   // wave per node, 4 waves/block

    hipLaunchKernelGGL(kU_prep, dim3(1), dim3(64), 0, stream, W1, atts1, attd1, us, ud);
    hipMemsetAsync(cnt, 0, (size_t)NN * sizeof(int), stream);
    hipLaunchKernelGGL(kB_hist, gE, blk, 0, stream, ei, cnt);
    hipLaunchKernelGGL(kC1_scan, dim3(NB1), blk, 0, stream, cnt, row, bsum);
    hipLaunchKernelGGL(kC2_scan, dim3(1), dim3(512), 0, stream, bsum);
    hipLaunchKernelGGL(kC3_fix, gN, blk, 0, stream, row, bsum, cursor);
    hipLaunchKernelGGL(kD_scatter, gE, blk, 0, stream, ei, cursor, esrc);
    hipLaunchKernelGGL(kE_l1agg, gW, blk, 0, stream, row, esrc, x, us, ud, W1, b1, W2, h2);
    hipLaunchKernelGGL(kF_l2agg, gW, blk, 0, stream, row, esrc, h2, atts2, attd2, b2, out);
}